// Round 1
// baseline (365.942 us; speedup 1.0000x reference)
//
#include <hip/hip_runtime.h>

#define DIM 768
#define NHEADS 12
#define HDIM 64
#define BATCH 8
#define LQ 1024
#define LKV 1024
#define ATTN_SCALE 0.125f

typedef __bf16 bf16;
typedef __bf16 bf16x4 __attribute__((ext_vector_type(4)));
typedef __bf16 bf16x8 __attribute__((ext_vector_type(8)));
typedef float f32x4 __attribute__((ext_vector_type(4)));

static __device__ __forceinline__ f32x4 mfma16(bf16x8 a, bf16x8 b, f32x4 c) {
    return __builtin_amdgcn_mfma_f32_16x16x32_bf16(a, b, c, 0, 0, 0);
}

// ---------------- fp32 -> bf16 convert ----------------
__global__ void cvt_f32_bf16(const float4* __restrict__ in, bf16x4* __restrict__ out, int n4) {
    int i = blockIdx.x * 256 + threadIdx.x;
    if (i < n4) {
        float4 v = in[i];
        bf16x4 o;
        o[0] = (bf16)v.x; o[1] = (bf16)v.y; o[2] = (bf16)v.z; o[3] = (bf16)v.w;
        out[i] = o;
    }
}

// ---------------- GEMM: C[M,N] = A[M,K] @ B[N,K]^T (+bias) ----------------
// 128x128 tile, BK=32, 4 waves (2x2 of 64x64), LDS pad to 40 elems/row.
template<int OUT_F32>
__global__ __launch_bounds__(256) void gemm_bt(
    const bf16* __restrict__ A, const bf16* __restrict__ B,
    void* __restrict__ Cp, const float* __restrict__ bias,
    int M, int N, int K)
{
    __shared__ bf16 As[128 * 40];
    __shared__ bf16 Bs[128 * 40];
    const int tid  = threadIdx.x;
    const int lane = tid & 63;
    const int wave = tid >> 6;
    const int wm = (wave >> 1) * 64;
    const int wn = (wave & 1) * 64;
    const int m0 = blockIdx.x * 128;
    const int n0 = blockIdx.y * 128;
    const int lq = lane & 15;
    const int quad = lane >> 4;
    const int row_l = tid >> 1;          // 0..127
    const int col_l = (tid & 1) * 16;    // 0 or 16

    f32x4 acc[4][4] = {};

    for (int k0 = 0; k0 < K; k0 += 32) {
        const bf16* ga = A + (size_t)(m0 + row_l) * K + k0 + col_l;
        const bf16* gb = B + (size_t)(n0 + row_l) * K + k0 + col_l;
        *(uint4*)&As[row_l * 40 + col_l]     = *(const uint4*)(ga);
        *(uint4*)&As[row_l * 40 + col_l + 8] = *(const uint4*)(ga + 8);
        *(uint4*)&Bs[row_l * 40 + col_l]     = *(const uint4*)(gb);
        *(uint4*)&Bs[row_l * 40 + col_l + 8] = *(const uint4*)(gb + 8);
        __syncthreads();

        bf16x8 a[4], b[4];
        #pragma unroll
        for (int i = 0; i < 4; i++)
            a[i] = *(const bf16x8*)&As[(wm + i * 16 + lq) * 40 + quad * 8];
        #pragma unroll
        for (int j = 0; j < 4; j++)
            b[j] = *(const bf16x8*)&Bs[(wn + j * 16 + lq) * 40 + quad * 8];
        #pragma unroll
        for (int i = 0; i < 4; i++)
            #pragma unroll
            for (int j = 0; j < 4; j++)
                acc[i][j] = mfma16(a[i], b[j], acc[i][j]);
        __syncthreads();
    }

    #pragma unroll
    for (int i = 0; i < 4; i++) {
        #pragma unroll
        for (int j = 0; j < 4; j++) {
            #pragma unroll
            for (int r = 0; r < 4; r++) {
                int rr = m0 + wm + i * 16 + quad * 4 + r;
                int cc = n0 + wn + j * 16 + lq;
                if (OUT_F32) {
                    ((float*)Cp)[(size_t)rr * N + cc] = acc[i][j][r] + bias[cc];
                } else {
                    ((bf16*)Cp)[(size_t)rr * N + cc] = (bf16)acc[i][j][r];
                }
            }
        }
    }
}

// ---------------- transpose V part of C2 -> Vt (B,H,D,LKV) ----------------
__global__ __launch_bounds__(256) void transpose_v(const bf16* __restrict__ C2, bf16* __restrict__ Vt) {
    __shared__ bf16 T[64 * 72];
    int bh = blockIdx.x;               // b*12+h
    int b = bh / NHEADS, h = bh % NHEADS;
    int kv0 = blockIdx.y * 64;
    int t = threadIdx.x;
    #pragma unroll
    for (int p = 0; p < 2; p++) {
        int row = (t >> 3) + p * 32;   // local lkv
        int c8  = (t & 7) * 8;         // local d
        const bf16* g = C2 + (size_t)(b * LKV + kv0 + row) * (2 * DIM) + DIM + h * HDIM + c8;
        *(uint4*)&T[row * 72 + c8] = *(const uint4*)g;
    }
    __syncthreads();
    #pragma unroll
    for (int p = 0; p < 2; p++) {
        int d  = (t >> 3) + p * 32;
        int l8 = (t & 7) * 8;
        bf16x8 tmp;
        #pragma unroll
        for (int j = 0; j < 8; j++) tmp[j] = T[(l8 + j) * 72 + d];
        bf16* o = Vt + ((size_t)(bh * HDIM + d)) * LKV + kv0 + l8;
        *(bf16x8*)o = tmp;
    }
}

// ---------------- fused attention ----------------
// grid: (LQ/64, B*H). block 256 = 4 waves; wave w owns q rows [w*16, w*16+16).
__global__ __launch_bounds__(256) void attn_kernel(
    const bf16* __restrict__ C1,   // (B*LQ, 768)  q-proj
    const bf16* __restrict__ C2,   // (B*LKV, 1536) kv-proj
    const bf16* __restrict__ Vt,   // (B*H*64, LKV)
    const float* __restrict__ pos, // (H, LQ, LKV)
    bf16* __restrict__ O)          // (B*LQ, 768)
{
    __shared__ bf16 Qs[64 * 72];
    __shared__ bf16 Ks[64 * 72];
    __shared__ bf16 Vs[64 * 72];
    __shared__ bf16 Ps[4 * 16 * 72];

    const int bh = blockIdx.y;
    const int b = bh / NHEADS, h = bh % NHEADS;
    const int q0 = blockIdx.x * 64;
    const int t = threadIdx.x;
    const int lane = t & 63;
    const int w = t >> 6;
    const int lq = lane & 15;
    const int quad = lane >> 4;

    // stage Q tile (64 q rows x 64 d)
    #pragma unroll
    for (int p = 0; p < 2; p++) {
        int row = (t >> 3) + p * 32;
        int c8  = (t & 7) * 8;
        const bf16* g = C1 + (size_t)(b * LQ + q0 + row) * DIM + h * HDIM + c8;
        *(uint4*)&Qs[row * 72 + c8] = *(const uint4*)g;
    }
    __syncthreads();
    bf16x8 qa[2];
    qa[0] = *(const bf16x8*)&Qs[(w * 16 + lq) * 72 +      quad * 8];
    qa[1] = *(const bf16x8*)&Qs[(w * 16 + lq) * 72 + 32 + quad * 8];
    __syncthreads();

    float m_r[4], l_r[4];
    f32x4 o_acc[4];
    #pragma unroll
    for (int r = 0; r < 4; r++) { m_r[r] = -1e30f; l_r[r] = 0.f; }
    #pragma unroll
    for (int od = 0; od < 4; od++) o_acc[od] = (f32x4){0.f, 0.f, 0.f, 0.f};

    bf16* Pw = &Ps[w * 16 * 72];

    for (int kv0 = 0; kv0 < LKV; kv0 += 64) {
        // stage K tile (64 kv x 64 d) and Vt tile (64 d x 64 kv)
        #pragma unroll
        for (int p = 0; p < 2; p++) {
            int row = (t >> 3) + p * 32;
            int c8  = (t & 7) * 8;
            *(uint4*)&Ks[row * 72 + c8] =
                *(const uint4*)(C2 + (size_t)(b * LKV + kv0 + row) * (2 * DIM) + h * HDIM + c8);
            *(uint4*)&Vs[row * 72 + c8] =
                *(const uint4*)(Vt + (size_t)(bh * HDIM + row) * LKV + kv0 + c8);
        }
        __syncthreads();

        // S = Q K^T  (16 q x 64 kv per wave), 4 col-blocks x 2 k-steps
        f32x4 s[4];
        #pragma unroll
        for (int nb = 0; nb < 4; nb++) {
            s[nb] = (f32x4){0.f, 0.f, 0.f, 0.f};
            #pragma unroll
            for (int kt = 0; kt < 2; kt++) {
                bf16x8 bk = *(const bf16x8*)&Ks[(nb * 16 + lq) * 72 + kt * 32 + quad * 8];
                s[nb] = mfma16(qa[kt], bk, s[nb]);
            }
        }

        // scale + positional bias
        float sv[4][4];
        const float* pr = pos + ((size_t)h * LQ + q0 + w * 16 + quad * 4) * LKV + kv0;
        #pragma unroll
        for (int r = 0; r < 4; r++)
            #pragma unroll
            for (int nb = 0; nb < 4; nb++)
                sv[nb][r] = s[nb][r] * ATTN_SCALE + pr[(size_t)r * LKV + nb * 16 + lq];

        // online softmax (rows live across 16 lanes of same quad)
        float alpha[4];
        #pragma unroll
        for (int r = 0; r < 4; r++) {
            float tmax = sv[0][r];
            #pragma unroll
            for (int nb = 1; nb < 4; nb++) tmax = fmaxf(tmax, sv[nb][r]);
            #pragma unroll
            for (int msk = 1; msk < 16; msk <<= 1)
                tmax = fmaxf(tmax, __shfl_xor(tmax, msk));
            float mn = fmaxf(m_r[r], tmax);
            alpha[r] = __expf(m_r[r] - mn);
            float rs = 0.f;
            #pragma unroll
            for (int nb = 0; nb < 4; nb++) {
                float pv = __expf(sv[nb][r] - mn);
                sv[nb][r] = pv;
                rs += pv;
            }
            #pragma unroll
            for (int msk = 1; msk < 16; msk <<= 1)
                rs += __shfl_xor(rs, msk);
            l_r[r] = l_r[r] * alpha[r] + rs;
            m_r[r] = mn;
        }
        #pragma unroll
        for (int od = 0; od < 4; od++)
            #pragma unroll
            for (int r = 0; r < 4; r++)
                o_acc[od][r] *= alpha[r];

        // P (C-layout) -> LDS -> A-layout
        #pragma unroll
        for (int r = 0; r < 4; r++)
            #pragma unroll
            for (int nb = 0; nb < 4; nb++)
                Pw[(quad * 4 + r) * 72 + nb * 16 + lq] = (bf16)sv[nb][r];

        // O += P @ V  (B-operand from Vs = V^T tile)
        #pragma unroll
        for (int od = 0; od < 4; od++) {
            #pragma unroll
            for (int kt = 0; kt < 2; kt++) {
                bf16x8 ap = *(const bf16x8*)&Pw[lq * 72 + kt * 32 + quad * 8];
                bf16x8 bv = *(const bf16x8*)&Vs[(od * 16 + lq) * 72 + kt * 32 + quad * 8];
                o_acc[od] = mfma16(ap, bv, o_acc[od]);
            }
        }
        __syncthreads();
    }

    // normalize + write O (B*LQ, 768) bf16
    #pragma unroll
    for (int r = 0; r < 4; r++) {
        float inv = 1.f / l_r[r];
        int orow = b * LQ + q0 + w * 16 + quad * 4 + r;
        #pragma unroll
        for (int od = 0; od < 4; od++) {
            O[(size_t)orow * DIM + h * HDIM + od * 16 + lq] = (bf16)(o_acc[od][r] * inv);
        }
    }
}

// ---------------- host ----------------
extern "C" void kernel_launch(void* const* d_in, const int* in_sizes, int n_in,
                              void* d_out, int out_size, void* d_ws, size_t ws_size,
                              hipStream_t stream) {
    const float* q     = (const float*)d_in[0];
    const float* kv    = (const float*)d_in[1];
    const float* pos   = (const float*)d_in[2];
    const float* Wq    = (const float*)d_in[3];
    const float* Wkv   = (const float*)d_in[4];
    const float* Wproj = (const float*)d_in[5];
    const float* bproj = (const float*)d_in[6];
    float* out = (float*)d_out;

    char* ws = (char*)d_ws;
    size_t off = 0;
    auto alloc = [&](size_t bytes) -> void* {
        void* p = ws + off;
        off += (bytes + 255) & ~(size_t)255;
        return p;
    };

    const int M  = BATCH * LQ;          // 8192
    bf16* qb   = (bf16*)alloc((size_t)M * DIM * 2);
    bf16* kvb  = (bf16*)alloc((size_t)M * DIM * 2);
    bf16* wqb  = (bf16*)alloc((size_t)DIM * DIM * 2);
    bf16* wkvb = (bf16*)alloc((size_t)2 * DIM * DIM * 2);
    bf16* wpb  = (bf16*)alloc((size_t)DIM * DIM * 2);
    bf16* C1   = (bf16*)alloc((size_t)M * DIM * 2);         // q proj
    bf16* C2   = (bf16*)alloc((size_t)M * 2 * DIM * 2);     // kv proj
    bf16* Vt   = (bf16*)alloc((size_t)BATCH * NHEADS * HDIM * LKV * 2);
    bf16* Ob   = (bf16*)alloc((size_t)M * DIM * 2);         // attention out

    auto cvt = [&](const float* src, bf16* dst, size_t n) {
        int n4 = (int)(n / 4);
        cvt_f32_bf16<<<(n4 + 255) / 256, 256, 0, stream>>>((const float4*)src, (bf16x4*)dst, n4);
    };
    cvt(q,     qb,   (size_t)M * DIM);
    cvt(kv,    kvb,  (size_t)M * DIM);
    cvt(Wq,    wqb,  (size_t)DIM * DIM);
    cvt(Wkv,   wkvb, (size_t)2 * DIM * DIM);
    cvt(Wproj, wpb,  (size_t)DIM * DIM);

    // C1 = q @ Wq^T  (8192 x 768)
    gemm_bt<0><<<dim3(M / 128, DIM / 128), 256, 0, stream>>>(qb, wqb, C1, nullptr, M, DIM, DIM);
    // C2 = kv @ Wkv^T (8192 x 1536)
    gemm_bt<0><<<dim3(M / 128, (2 * DIM) / 128), 256, 0, stream>>>(kvb, wkvb, C2, nullptr, M, 2 * DIM, DIM);
    // Vt
    transpose_v<<<dim3(BATCH * NHEADS, LKV / 64), 256, 0, stream>>>(C2, Vt);
    // attention
    attn_kernel<<<dim3(LQ / 64, BATCH * NHEADS), 256, 0, stream>>>(C1, C2, Vt, pos, Ob);
    // out = Ob @ Wproj^T + bproj (fp32)
    gemm_bt<1><<<dim3(M / 128, DIM / 128), 256, 0, stream>>>(Ob, wpb, out, bproj, M, DIM, DIM);
}

// Round 2
// 331.667 us; speedup vs baseline: 1.1033x; 1.1033x over previous
//
#include <hip/hip_runtime.h>

#define DIM 768
#define NHEADS 12
#define HDIM 64
#define BATCH 8
#define LQ 1024
#define LKV 1024
#define ATTN_SCALE 0.125f

typedef __bf16 bf16;
typedef __bf16 bf16x4 __attribute__((ext_vector_type(4)));
typedef __bf16 bf16x8 __attribute__((ext_vector_type(8)));
typedef short s16x4 __attribute__((ext_vector_type(4)));
typedef float f32x4 __attribute__((ext_vector_type(4)));

union B4 { bf16x4 h; s16x4 s; };

static __device__ __forceinline__ f32x4 mfma_k32(bf16x8 a, bf16x8 b, f32x4 c) {
    return __builtin_amdgcn_mfma_f32_16x16x32_bf16(a, b, c, 0, 0, 0);
}
// legacy gfx90a-series 16x16x16 bf16 MFMA (K=16, 4 elems/lane), valid on gfx950
static __device__ __forceinline__ f32x4 mfma_k16(s16x4 a, s16x4 b, f32x4 c) {
    return __builtin_amdgcn_mfma_f32_16x16x16bf16_1k(a, b, c, 0, 0, 0);
}

// ---------------- GEMM: C[M,N] = A[M,K] @ B[N,K]^T (+bias) ----------------
// 128x128 tile, BK=32, 4 waves (2x2 of 64x64), LDS pad to 40 elems/row.
// B is always fp32 (weights), converted during staging. A is fp32 or bf16.
template<int OUT_F32, int A_BF16>
__global__ __launch_bounds__(256) void gemm_bt(
    const void* __restrict__ Ap, const float* __restrict__ B,
    void* __restrict__ Cp, const float* __restrict__ bias,
    int M, int N, int K)
{
    __shared__ bf16 As[128 * 40];
    __shared__ bf16 Bs[128 * 40];
    const int tid  = threadIdx.x;
    const int lane = tid & 63;
    const int wave = tid >> 6;
    const int wm = (wave >> 1) * 64;
    const int wn = (wave & 1) * 64;
    const int m0 = blockIdx.x * 128;
    const int n0 = blockIdx.y * 128;
    const int lq = lane & 15;
    const int quad = lane >> 4;
    const int row_l = tid >> 1;          // 0..127
    const int col_l = (tid & 1) * 16;    // 0 or 16

    f32x4 acc[4][4] = {};

    for (int k0 = 0; k0 < K; k0 += 32) {
        if (A_BF16) {
            const bf16* ga = (const bf16*)Ap + (size_t)(m0 + row_l) * K + k0 + col_l;
            *(uint4*)&As[row_l * 40 + col_l]     = *(const uint4*)(ga);
            *(uint4*)&As[row_l * 40 + col_l + 8] = *(const uint4*)(ga + 8);
        } else {
            const float* ga = (const float*)Ap + (size_t)(m0 + row_l) * K + k0 + col_l;
            float4 f0 = *(const float4*)(ga);
            float4 f1 = *(const float4*)(ga + 4);
            float4 f2 = *(const float4*)(ga + 8);
            float4 f3 = *(const float4*)(ga + 12);
            bf16x8 h0, h1;
            h0[0]=(bf16)f0.x; h0[1]=(bf16)f0.y; h0[2]=(bf16)f0.z; h0[3]=(bf16)f0.w;
            h0[4]=(bf16)f1.x; h0[5]=(bf16)f1.y; h0[6]=(bf16)f1.z; h0[7]=(bf16)f1.w;
            h1[0]=(bf16)f2.x; h1[1]=(bf16)f2.y; h1[2]=(bf16)f2.z; h1[3]=(bf16)f2.w;
            h1[4]=(bf16)f3.x; h1[5]=(bf16)f3.y; h1[6]=(bf16)f3.z; h1[7]=(bf16)f3.w;
            *(bf16x8*)&As[row_l * 40 + col_l]     = h0;
            *(bf16x8*)&As[row_l * 40 + col_l + 8] = h1;
        }
        {
            const float* gb = B + (size_t)(n0 + row_l) * K + k0 + col_l;
            float4 f0 = *(const float4*)(gb);
            float4 f1 = *(const float4*)(gb + 4);
            float4 f2 = *(const float4*)(gb + 8);
            float4 f3 = *(const float4*)(gb + 12);
            bf16x8 h0, h1;
            h0[0]=(bf16)f0.x; h0[1]=(bf16)f0.y; h0[2]=(bf16)f0.z; h0[3]=(bf16)f0.w;
            h0[4]=(bf16)f1.x; h0[5]=(bf16)f1.y; h0[6]=(bf16)f1.z; h0[7]=(bf16)f1.w;
            h1[0]=(bf16)f2.x; h1[1]=(bf16)f2.y; h1[2]=(bf16)f2.z; h1[3]=(bf16)f2.w;
            h1[4]=(bf16)f3.x; h1[5]=(bf16)f3.y; h1[6]=(bf16)f3.z; h1[7]=(bf16)f3.w;
            *(bf16x8*)&Bs[row_l * 40 + col_l]     = h0;
            *(bf16x8*)&Bs[row_l * 40 + col_l + 8] = h1;
        }
        __syncthreads();

        bf16x8 a[4], b[4];
        #pragma unroll
        for (int i = 0; i < 4; i++)
            a[i] = *(const bf16x8*)&As[(wm + i * 16 + lq) * 40 + quad * 8];
        #pragma unroll
        for (int j = 0; j < 4; j++)
            b[j] = *(const bf16x8*)&Bs[(wn + j * 16 + lq) * 40 + quad * 8];
        #pragma unroll
        for (int i = 0; i < 4; i++)
            #pragma unroll
            for (int j = 0; j < 4; j++)
                acc[i][j] = mfma_k32(a[i], b[j], acc[i][j]);
        __syncthreads();
    }

    #pragma unroll
    for (int i = 0; i < 4; i++) {
        #pragma unroll
        for (int j = 0; j < 4; j++) {
            #pragma unroll
            for (int r = 0; r < 4; r++) {
                int rr = m0 + wm + i * 16 + quad * 4 + r;
                int cc = n0 + wn + j * 16 + lq;
                if (OUT_F32) {
                    ((float*)Cp)[(size_t)rr * N + cc] = acc[i][j][r] + bias[cc];
                } else {
                    ((bf16*)Cp)[(size_t)rr * N + cc] = (bf16)acc[i][j][r];
                }
            }
        }
    }
}

// ---------------- transpose V part of C2 -> Vt (B,H,D,LKV) ----------------
__global__ __launch_bounds__(256) void transpose_v(const bf16* __restrict__ C2, bf16* __restrict__ Vt) {
    __shared__ bf16 T[64 * 72];
    int bh = blockIdx.x;               // b*12+h
    int b = bh / NHEADS, h = bh % NHEADS;
    int kv0 = blockIdx.y * 64;
    int t = threadIdx.x;
    #pragma unroll
    for (int p = 0; p < 2; p++) {
        int row = (t >> 3) + p * 32;   // local lkv
        int c8  = (t & 7) * 8;         // local d
        const bf16* g = C2 + (size_t)(b * LKV + kv0 + row) * (2 * DIM) + DIM + h * HDIM + c8;
        *(uint4*)&T[row * 72 + c8] = *(const uint4*)g;
    }
    __syncthreads();
    #pragma unroll
    for (int p = 0; p < 2; p++) {
        int d  = (t >> 3) + p * 32;
        int l8 = (t & 7) * 8;
        bf16x8 tmp;
        #pragma unroll
        for (int j = 0; j < 8; j++) tmp[j] = T[(l8 + j) * 72 + d];
        bf16* o = Vt + ((size_t)(bh * HDIM + d)) * LKV + kv0 + l8;
        *(bf16x8*)o = tmp;
    }
}

// ---------------- fused attention (transposed-S formulation) ----------------
// grid: (LQ/64, H*B). block 256 = 4 waves; wave w owns q rows [w*16, w*16+16),
// one q row per lane (q = w*16 + (lane&15)).
// S^T = K Q^T : C-layout rows = kv (quad*4+r), cols = q (lane&15).
//   -> pos bias loads are contiguous float4 per lane
//   -> softmax reduce over kv = in-lane (16 vals) + shfl_xor 16,32
//   -> P regs are exactly the B-operand of mfma 16x16x16 (k=quad*4+j), no LDS round-trip
// PV: O^T[d][q] += Vt-tile (A-op) * P (B-op), accumulated in C-layout (rows=d, cols=q).
__global__ __launch_bounds__(256) void attn_kernel(
    const bf16* __restrict__ C1,   // (B*LQ, 768)  q-proj
    const bf16* __restrict__ C2,   // (B*LKV, 1536) kv-proj
    const bf16* __restrict__ Vt,   // (B*H*64, LKV)
    const float* __restrict__ pos, // (H, LQ, LKV)
    bf16* __restrict__ O)          // (B*LQ, 768)
{
    __shared__ bf16 Qs[64 * 72];
    __shared__ bf16 Ks[64 * 72];   // [kv][d]
    __shared__ bf16 Vs[64 * 72];   // [d][kv]

    const int by = blockIdx.y;     // h-major for pos L2 locality
    const int h = by >> 3, b = by & 7;
    const int bh = b * NHEADS + h;
    const int q0 = blockIdx.x * 64;
    const int t = threadIdx.x;
    const int lane = t & 63;
    const int w = t >> 6;
    const int lq = lane & 15;
    const int quad = lane >> 4;

    // stage Q tile (64 q rows x 64 d)
    #pragma unroll
    for (int p = 0; p < 2; p++) {
        int row = (t >> 3) + p * 32;
        int c8  = (t & 7) * 8;
        const bf16* g = C1 + (size_t)(b * LQ + q0 + row) * DIM + h * HDIM + c8;
        *(uint4*)&Qs[row * 72 + c8] = *(const uint4*)g;
    }
    __syncthreads();
    // Q fragment = B-operand of S^T mfma: B[n=q=lq][k=d=kt*32+quad*8+j]
    bf16x8 qa[2];
    qa[0] = *(const bf16x8*)&Qs[(w * 16 + lq) * 72 +      quad * 8];
    qa[1] = *(const bf16x8*)&Qs[(w * 16 + lq) * 72 + 32 + quad * 8];
    __syncthreads();

    float m_r = -1e30f, l_r = 0.f;
    f32x4 o_acc[4] = {};   // O^T: rows d = dblk*16+quad*4+r, col q = lq

    const float4* pos4 = (const float4*)(pos + ((size_t)h * LQ + q0 + w * 16 + lq) * LKV);

    for (int kv0 = 0; kv0 < LKV; kv0 += 64) {
        // stage K tile [kv][d] and Vt tile [d][kv]
        #pragma unroll
        for (int p = 0; p < 2; p++) {
            int row = (t >> 3) + p * 32;
            int c8  = (t & 7) * 8;
            *(uint4*)&Ks[row * 72 + c8] =
                *(const uint4*)(C2 + (size_t)(b * LKV + kv0 + row) * (2 * DIM) + h * HDIM + c8);
            *(uint4*)&Vs[row * 72 + c8] =
                *(const uint4*)(Vt + (size_t)(bh * HDIM + row) * LKV + kv0 + c8);
        }
        __syncthreads();

        // pos bias: contiguous float4 per lane (kv = kvblk*16 + quad*4 + r)
        float4 pb[4];
        #pragma unroll
        for (int kvblk = 0; kvblk < 4; kvblk++)
            pb[kvblk] = pos4[(kv0 >> 2) + kvblk * 4 + quad];

        // S^T = K Q^T : per wave, 4 kv-blocks (m) x 1 q-block (n), 2 k-steps
        f32x4 s[4];
        #pragma unroll
        for (int kvblk = 0; kvblk < 4; kvblk++) {
            s[kvblk] = (f32x4){0.f, 0.f, 0.f, 0.f};
            #pragma unroll
            for (int kt = 0; kt < 2; kt++) {
                bf16x8 ak = *(const bf16x8*)&Ks[(kvblk * 16 + lq) * 72 + kt * 32 + quad * 8];
                s[kvblk] = mfma_k32(ak, qa[kt], s[kvblk]);
            }
        }

        float sv[4][4];
        #pragma unroll
        for (int kvblk = 0; kvblk < 4; kvblk++) {
            sv[kvblk][0] = s[kvblk][0] * ATTN_SCALE + pb[kvblk].x;
            sv[kvblk][1] = s[kvblk][1] * ATTN_SCALE + pb[kvblk].y;
            sv[kvblk][2] = s[kvblk][2] * ATTN_SCALE + pb[kvblk].z;
            sv[kvblk][3] = s[kvblk][3] * ATTN_SCALE + pb[kvblk].w;
        }

        // online softmax over kv for this lane's q row
        float tmax = sv[0][0];
        #pragma unroll
        for (int kvblk = 0; kvblk < 4; kvblk++)
            #pragma unroll
            for (int r = 0; r < 4; r++)
                tmax = fmaxf(tmax, sv[kvblk][r]);
        tmax = fmaxf(tmax, __shfl_xor(tmax, 16));
        tmax = fmaxf(tmax, __shfl_xor(tmax, 32));
        float mn = fmaxf(m_r, tmax);
        float alpha = __expf(m_r - mn);
        float rs = 0.f;
        B4 pfrag[4];
        #pragma unroll
        for (int kvblk = 0; kvblk < 4; kvblk++) {
            #pragma unroll
            for (int r = 0; r < 4; r++) {
                float pv = __expf(sv[kvblk][r] - mn);
                rs += pv;
                pfrag[kvblk].h[r] = (bf16)pv;
            }
        }
        rs += __shfl_xor(rs, 16);
        rs += __shfl_xor(rs, 32);
        l_r = l_r * alpha + rs;
        m_r = mn;

        #pragma unroll
        for (int dblk = 0; dblk < 4; dblk++) {
            o_acc[dblk][0] *= alpha; o_acc[dblk][1] *= alpha;
            o_acc[dblk][2] *= alpha; o_acc[dblk][3] *= alpha;
        }

        // O^T += V^T-tile (A-op: A[m=d=lq][k=kv=quad*4+j]) * P (B-op from regs)
        #pragma unroll
        for (int dblk = 0; dblk < 4; dblk++) {
            #pragma unroll
            for (int kvblk = 0; kvblk < 4; kvblk++) {
                s16x4 va = *(const s16x4*)&Vs[(dblk * 16 + lq) * 72 + kvblk * 16 + quad * 4];
                o_acc[dblk] = mfma_k16(va, pfrag[kvblk].s, o_acc[dblk]);
            }
        }
        __syncthreads();
    }

    // normalize + write O: lane's column q = lq, rows d = dblk*16+quad*4+r
    float inv = 1.f / l_r;
    const size_t orow = (size_t)(b * LQ + q0 + w * 16 + lq) * DIM + h * HDIM;
    #pragma unroll
    for (int dblk = 0; dblk < 4; dblk++) {
        B4 ob;
        #pragma unroll
        for (int r = 0; r < 4; r++) ob.h[r] = (bf16)(o_acc[dblk][r] * inv);
        *(s16x4*)&O[orow + dblk * 16 + quad * 4] = ob.s;
    }
}

// ---------------- host ----------------
extern "C" void kernel_launch(void* const* d_in, const int* in_sizes, int n_in,
                              void* d_out, int out_size, void* d_ws, size_t ws_size,
                              hipStream_t stream) {
    const float* q     = (const float*)d_in[0];
    const float* kv    = (const float*)d_in[1];
    const float* pos   = (const float*)d_in[2];
    const float* Wq    = (const float*)d_in[3];
    const float* Wkv   = (const float*)d_in[4];
    const float* Wproj = (const float*)d_in[5];
    const float* bproj = (const float*)d_in[6];
    float* out = (float*)d_out;

    char* ws = (char*)d_ws;
    size_t off = 0;
    auto alloc = [&](size_t bytes) -> void* {
        void* p = ws + off;
        off += (bytes + 255) & ~(size_t)255;
        return p;
    };

    const int M  = BATCH * LQ;          // 8192
    bf16* C1   = (bf16*)alloc((size_t)M * DIM * 2);         // q proj
    bf16* C2   = (bf16*)alloc((size_t)M * 2 * DIM * 2);     // kv proj
    bf16* Vt   = (bf16*)alloc((size_t)BATCH * NHEADS * HDIM * LKV * 2);
    bf16* Ob   = (bf16*)alloc((size_t)M * DIM * 2);         // attention out

    // C1 = q @ Wq^T  (8192 x 768), cvt fused into staging
    gemm_bt<0, 0><<<dim3(M / 128, DIM / 128), 256, 0, stream>>>(q, Wq, C1, nullptr, M, DIM, DIM);
    // C2 = kv @ Wkv^T (8192 x 1536)
    gemm_bt<0, 0><<<dim3(M / 128, (2 * DIM) / 128), 256, 0, stream>>>(kv, Wkv, C2, nullptr, M, 2 * DIM, DIM);
    // Vt
    transpose_v<<<dim3(BATCH * NHEADS, LKV / 64), 256, 0, stream>>>(C2, Vt);
    // attention
    attn_kernel<<<dim3(LQ / 64, NHEADS * BATCH), 256, 0, stream>>>(C1, C2, Vt, pos, Ob);
    // out = Ob @ Wproj^T + bproj (fp32)
    gemm_bt<1, 1><<<dim3(M / 128, DIM / 128), 256, 0, stream>>>(Ob, Wproj, out, bproj, M, DIM, DIM);
}